// Round 6
// baseline (591.824 us; speedup 1.0000x reference)
//
#include <hip/hip_runtime.h>
#include <hip/hip_bf16.h>

// ---------------------------------------------------------------------------
// GCN: h = relu(GCNConv(x,W1,b1)); x1 = relu(GCNConv(h,W2,b2));
//      x2 = meanpool(x1,batch); out = log_softmax(relu(x2@fc1+b)@fc2+b)
//
// R6: place rebuilt as XCD-range histogram binning: 64 blocks, range=blk%8
// (-> XCD-local slot stores, L2-resident full-line writeback), LDS histogram
// dedups cnt atomics 1.6M -> ~390K (R5: 3.2M coherent-point transactions =
// 27G/s wall = 120us). Overflow handling folded inline into degfin/gather
// (flag-gated fixup kernels removed); dinv folded into degfin. 9 launches.
// ---------------------------------------------------------------------------

#define CAP 64
#define OVFCAP 8192
#define MAXNR 6400   // max nodes per range for the histogram place path

// Histogram place: range r = blockIdx%8 (maps to XCD r), chunk j = blockIdx/8.
// Pass B: LDS histogram of chunk's in-range edges. Pass C: one global atomic
// per touched node reserves [g,g+h) in bucket. Pass D: write records at
// deterministic positions (LDS cursor). Stores are XCD-local -> L2-resident.
__global__ __launch_bounds__(1024)
void place_hist_kernel(const int* __restrict__ rows, const int* __restrict__ cols,
                       const float* __restrict__ ew, int* __restrict__ cnt,
                       unsigned* __restrict__ slot, int4* __restrict__ ovf,
                       int* __restrict__ ovfcnt, int E, int N) {
    __shared__ int hist[MAXNR];
    const int r = blockIdx.x & 7;
    const int j = blockIdx.x >> 3;
    const int NCH = gridDim.x >> 3;
    const int NR = (N + 7) >> 3;
    const int base = r * NR;
    const int hi = min(base + NR, N);
    const int CS = (E + NCH - 1) / NCH;
    const int e0 = j * CS, e1 = min(e0 + CS, E);
    const int t = threadIdx.x;
    for (int n = t; n < NR; n += 1024) hist[n] = 0;
    __syncthreads();
    for (int e = e0 + t; e < e1; e += 1024) {
        int c = cols[e];
        if (c >= base && c < hi) atomicAdd(&hist[c - base], 1);
    }
    __syncthreads();
    for (int n = t; n < NR; n += 1024) {
        int h = hist[n];
        if (h > 0) hist[n] = atomicAdd(&cnt[base + n], h);   // global base
    }
    __syncthreads();
    for (int e = e0 + t; e < e1; e += 1024) {
        int c = cols[e];
        if (c >= base && c < hi) {
            int pos = atomicAdd(&hist[c - base], 1);          // LDS cursor
            int q = (int)(ew[e] * 32768.0f);
            if (q > 32767) q = 32767;
            unsigned rec = ((unsigned)rows[e] << 15) | (unsigned)q;
            if (pos < CAP) {
                slot[(size_t)c * CAP + pos] = rec;
            } else {
                int o = atomicAdd(ovfcnt, 1);
                if (o < OVFCAP) ovf[o] = make_int4(rows[e], c, q, 0);
            }
        }
    }
}

// Fallback for NR > MAXNR (not taken for this problem size): per-edge atomics.
__global__ void place_simple_kernel(const int* __restrict__ rows, const int* __restrict__ cols,
                                    const float* __restrict__ ew, int* __restrict__ cnt,
                                    unsigned* __restrict__ slot, int4* __restrict__ ovf,
                                    int* __restrict__ ovfcnt, int E) {
    int e = blockIdx.x * 256 + threadIdx.x;
    if (e >= E) return;
    int r = rows[e], c = cols[e];
    int q = (int)(ew[e] * 32768.0f);
    if (q > 32767) q = 32767;
    int pos = atomicAdd(&cnt[c], 1);
    if (pos < CAP) {
        slot[(size_t)c * CAP + pos] = ((unsigned)r << 15) | (unsigned)q;
    } else {
        int o = atomicAdd(ovfcnt, 1);
        if (o < OVFCAP) ovf[o] = make_int4(r, c, q, 0);
    }
}

// dinv[i] = rsqrt(sum of bucket weights (+ ovf entries if cnt>CAP) + 1).
__global__ void degfin_kernel(const unsigned* __restrict__ slot, const int* __restrict__ cnt,
                              const int4* __restrict__ ovf, const int* __restrict__ ovfcnt,
                              float* __restrict__ dinv, int N) {
    const int w = threadIdx.x >> 6, lane = threadIdx.x & 63;
    const int i = blockIdx.x * 4 + w;
    if (i >= N) return;
    int mraw = cnt[i];
    int m = mraw > CAP ? CAP : mraw;
    float v = 0.f;
    if (lane < m) v = (float)(slot[(size_t)i * CAP + lane] & 32767u);
    if (mraw > CAP) {
        int oc = *ovfcnt; if (oc > OVFCAP) oc = OVFCAP;
        for (int k = lane; k < oc; k += 64)
            if (ovf[k].y == i) v += (float)ovf[k].z;
    }
    #pragma unroll
    for (int off = 1; off < 64; off <<= 1) v += __shfl_xor(v, off);
    if (lane == 0) dinv[i] = rsqrtf(v * (1.0f / 32768.0f) + 1.0f);
}

// out_sliced[slice][M][SW] = (A[M][128] @ W[128][BN]) * dinv[row] * 2^-15.
template <int BN, int S>
__global__ void gemm_kernel(const float* __restrict__ A, const float* __restrict__ W,
                            const float* __restrict__ dinv, float* __restrict__ out, int M) {
    constexpr int K = 128;
    constexpr int BK = 32;
    constexpr int SW = BN / S;
    constexpr int CG = BN / 4;
    constexpr int RG = 256 / CG;
    constexpr int BM = RG * 4;
    __shared__ float xs[BM][BK + 4];
    __shared__ float ws[BK][BN];
    const int t = threadIdx.x;
    const int cg = t % CG, rg = t / CG;
    const int c0 = cg * 4, r0 = rg * 4;
    const int rowBase = blockIdx.x * BM;
    float acc[4][4] = {};
    for (int k0 = 0; k0 < K; k0 += BK) {
        constexpr int XL = BM * BK / (256 * 4);
        #pragma unroll
        for (int i = 0; i < XL; ++i) {
            int f = (t + i * 256) * 4;
            int rr = f / BK, kk = f % BK;
            int grow = rowBase + rr;
            float4 v = (grow < M) ? *(const float4*)&A[(size_t)grow * K + k0 + kk]
                                  : make_float4(0.f, 0.f, 0.f, 0.f);
            *(float4*)&xs[rr][kk] = v;
        }
        constexpr int WL = BK * BN / (256 * 4);
        #pragma unroll
        for (int i = 0; i < WL; ++i) {
            int f = (t + i * 256) * 4;
            int kk = f / BN, cc = f % BN;
            *(float4*)&ws[kk][cc] = *(const float4*)&W[(size_t)(k0 + kk) * BN + cc];
        }
        __syncthreads();
        #pragma unroll
        for (int kk = 0; kk < BK; ++kk) {
            float4 wv = *(float4*)&ws[kk][c0];
            float xv[4];
            #pragma unroll
            for (int i = 0; i < 4; ++i) xv[i] = xs[r0 + i][kk];
            #pragma unroll
            for (int i = 0; i < 4; ++i) {
                acc[i][0] += xv[i] * wv.x;
                acc[i][1] += xv[i] * wv.y;
                acc[i][2] += xv[i] * wv.z;
                acc[i][3] += xv[i] * wv.w;
            }
        }
        __syncthreads();
    }
    const int slice = c0 / SW, cw = c0 % SW;
    float* dst0 = out + (size_t)slice * M * SW + cw;
    #pragma unroll
    for (int i = 0; i < 4; ++i) {
        int grow = rowBase + r0 + i;
        if (grow < M) {
            float s = dinv[grow] * (1.0f / 32768.0f);
            *(float4*)&dst0[(size_t)grow * SW] =
                make_float4(acc[i][0] * s, acc[i][1] * s, acc[i][2] * s, acc[i][3] * s);
        }
    }
}

// Sliced aggregation (slice = blockIdx%S -> XCD-local sub-table). Wave handles
// 4 nodes (lane = nd*16 + e*4 + cg). Table prescaled by dinv[row]*2^-15 so
// coef = (float)q15. Overflow edges handled inline (cnt>CAP -> scan ovf).
// Epilogue: relu(d*acc + xs_self*(d*32768) + b).
template <int F, int S>
__global__ void gather_kernel(const float* __restrict__ xsb, const unsigned* __restrict__ slot,
                              const int* __restrict__ cnt, const float* __restrict__ dinv,
                              const float* __restrict__ b, const int4* __restrict__ ovf,
                              const int* __restrict__ ovfcnt, float* __restrict__ out, int N) {
    constexpr int SW = F / S;        // 16
    constexpr int LG = SW / 4;       // 4 lanes per edge
    constexpr int EPN = 4;           // edges in flight per node
    constexpr int NPW = 64 / (LG * EPN);  // 4 nodes per wave
    const int slice = blockIdx.x % S;
    const int grp = blockIdx.x / S;
    const int w = threadIdx.x >> 6, lane = threadIdx.x & 63;
    const int cg = lane % LG;
    const int e  = (lane / LG) % EPN;
    const int nd = lane / (LG * EPN);
    const int i = (grp * 4 + w) * NPW + nd;
    const bool iv = (i < N);
    const int ic = iv ? i : 0;
    const float4* xs4 = (const float4*)(xsb + (size_t)slice * N * SW);
    int mraw = iv ? cnt[ic] : 0;
    int m = mraw > CAP ? CAP : mraw;
    const unsigned* bkt = slot + (size_t)ic * CAP;
    float4 acc = make_float4(0.f, 0.f, 0.f, 0.f);
    int j = e;
    for (; j + EPN < m; j += 2 * EPN) {
        unsigned u0 = bkt[j], u1 = bkt[j + EPN];
        int r0 = u0 >> 15, r1 = u1 >> 15;
        float c0 = (float)(u0 & 32767u);
        float c1 = (float)(u1 & 32767u);
        float4 v0 = xs4[r0 * LG + cg];
        float4 v1 = xs4[r1 * LG + cg];
        acc.x += v0.x * c0 + v1.x * c1;
        acc.y += v0.y * c0 + v1.y * c1;
        acc.z += v0.z * c0 + v1.z * c1;
        acc.w += v0.w * c0 + v1.w * c1;
    }
    if (j < m) {
        unsigned u = bkt[j];
        int r = u >> 15;
        float c = (float)(u & 32767u);
        float4 v = xs4[r * LG + cg];
        acc.x += v.x * c; acc.y += v.y * c; acc.z += v.z * c; acc.w += v.w * c;
    }
    if (mraw > CAP) {                     // inline overflow (normally skipped)
        int oc = *ovfcnt; if (oc > OVFCAP) oc = OVFCAP;
        for (int k = e; k < oc; k += EPN) {
            int4 rec = ovf[k];
            if (rec.y == i) {
                float c = (float)rec.z;
                float4 v = xs4[rec.x * LG + cg];
                acc.x += v.x * c; acc.y += v.y * c; acc.z += v.z * c; acc.w += v.w * c;
            }
        }
    }
    // reduce over e (EPN=4): two butterfly steps
    acc.x += __shfl_xor(acc.x, LG);     acc.y += __shfl_xor(acc.y, LG);
    acc.z += __shfl_xor(acc.z, LG);     acc.w += __shfl_xor(acc.w, LG);
    acc.x += __shfl_xor(acc.x, 2 * LG); acc.y += __shfl_xor(acc.y, 2 * LG);
    acc.z += __shfl_xor(acc.z, 2 * LG); acc.w += __shfl_xor(acc.w, 2 * LG);
    if (e == 0 && iv) {
        float d = dinv[i];
        float sd = d * 32768.0f;
        float4 xv = xs4[i * LG + cg];
        float4 bb = *(const float4*)&b[slice * SW + cg * 4];
        float4 o;
        o.x = fmaxf(acc.x * d + xv.x * sd + bb.x, 0.f);
        o.y = fmaxf(acc.y * d + xv.y * sd + bb.y, 0.f);
        o.z = fmaxf(acc.z * d + xv.z * sd + bb.z, 0.f);
        o.w = fmaxf(acc.w * d + xv.w * sd + bb.w, 0.f);
        *(float4*)&out[(size_t)i * F + slice * SW + cg * 4] = o;
    }
}

// sums[batch[n]] += x1[n]; cnt[batch[n]] += 1 (sorted batch, boundary atomics)
__global__ void pool_kernel(const float* __restrict__ x1, const int* __restrict__ batch,
                            float* __restrict__ sums, float* __restrict__ cnt, int N) {
    constexpr int QG = 16, S = 16, ITER = 16;
    int t = threadIdx.x;
    int q = t % QG, s = t / QG;
    int n0 = blockIdx.x * (S * ITER) + s * ITER;
    float4 acc = make_float4(0.f, 0.f, 0.f, 0.f);
    float cacc = 0.f;
    int gcur = -1;
    for (int i = 0; i < ITER; ++i) {
        int n = n0 + i;
        if (n >= N) break;
        int gid = batch[n];
        if (gid != gcur) {
            if (gcur >= 0) {
                float* dst = &sums[gcur * 64 + q * 4];
                atomicAdd(dst + 0, acc.x);
                atomicAdd(dst + 1, acc.y);
                atomicAdd(dst + 2, acc.z);
                atomicAdd(dst + 3, acc.w);
                if (q == 0) atomicAdd(&cnt[gcur], cacc);
            }
            gcur = gid;
            acc = make_float4(0.f, 0.f, 0.f, 0.f);
            cacc = 0.f;
        }
        float4 a = ((const float4*)x1)[n * QG + q];
        acc.x += a.x; acc.y += a.y; acc.z += a.z; acc.w += a.w;
        if (q == 0) cacc += 1.f;
    }
    if (gcur >= 0) {
        float* dst = &sums[gcur * 64 + q * 4];
        atomicAdd(dst + 0, acc.x);
        atomicAdd(dst + 1, acc.y);
        atomicAdd(dst + 2, acc.z);
        atomicAdd(dst + 3, acc.w);
        if (q == 0) atomicAdd(&cnt[gcur], cacc);
    }
}

// Final MLP head + log_softmax, one block. G=64 graphs.
__global__ void head_kernel(const float* __restrict__ sums, const float* __restrict__ cnt,
                            const float* __restrict__ fc1W, const float* __restrict__ fc1b,
                            const float* __restrict__ fc2W, const float* __restrict__ fc2b,
                            float* __restrict__ out) {
    __shared__ float x2[64 * 64];
    __shared__ float h[64 * 128];
    __shared__ float logits[64 * 2];
    int t = threadIdx.x;
    for (int i = t; i < 64 * 64; i += 256) {
        int g = i / 64;
        x2[i] = sums[i] / fmaxf(cnt[g], 1.f);
    }
    __syncthreads();
    for (int i = t; i < 64 * 128; i += 256) {
        int g = i / 128, k = i % 128;
        float a = fc1b[k];
        #pragma unroll 8
        for (int j = 0; j < 64; ++j) a += x2[g * 64 + j] * fc1W[j * 128 + k];
        h[i] = fmaxf(a, 0.f);
    }
    __syncthreads();
    if (t < 128) {
        int g = t / 2, m = t % 2;
        float a = fc2b[m];
        #pragma unroll 8
        for (int k = 0; k < 128; ++k) a += h[g * 128 + k] * fc2W[k * 2 + m];
        logits[t] = a;
    }
    __syncthreads();
    if (t < 128) {
        int g = t / 2, m = t % 2;
        float l0 = logits[g * 2 + 0], l1 = logits[g * 2 + 1];
        float mx = fmaxf(l0, l1);
        float lse = mx + logf(expf(l0 - mx) + expf(l1 - mx));
        out[t] = (m == 0 ? l0 : l1) - lse;
    }
}

extern "C" void kernel_launch(void* const* d_in, const int* in_sizes, int n_in,
                              void* d_out, int out_size, void* d_ws, size_t ws_size,
                              hipStream_t stream) {
    const float* x      = (const float*)d_in[0];
    const int*   eidx   = (const int*)d_in[1];
    const float* ew     = (const float*)d_in[2];
    const int*   batch  = (const int*)d_in[3];
    const float* W1     = (const float*)d_in[4];
    const float* b1     = (const float*)d_in[5];
    const float* W2     = (const float*)d_in[6];
    const float* b2     = (const float*)d_in[7];
    const float* fc1W   = (const float*)d_in[8];
    const float* fc1b   = (const float*)d_in[9];
    const float* fc2W   = (const float*)d_in[10];
    const float* fc2b   = (const float*)d_in[11];
    float* out = (float*)d_out;

    const int N = in_sizes[3];          // 50000 nodes
    const int E = in_sizes[2];          // 1600000 edges
    const int* rows = eidx;
    const int* cols = eidx + E;

    float* ws = (float*)d_ws;
    size_t off = 0;
    auto alloc = [&](size_t n) { float* p = ws + off; off += (n + 15) & ~(size_t)15; return p; };
    // --- zero-initialized region ---
    int*      cnt    = (int*)alloc(N);
    float*    sums   = alloc(64 * 64);
    float*    cntf   = alloc(16);
    int*      ovfcnt = (int*)alloc(16);
    size_t zfloats = off;
    // --- rest ---
    float*    dinv   = alloc(N);
    unsigned* slot   = (unsigned*)alloc((size_t)N * CAP);
    int4*     ovf    = (int4*)alloc((size_t)OVFCAP * 4);
    float*    bufA   = alloc((size_t)N * 128);   // xw1s; later xw2s (lo) + x1 (hi)
    float*    bufB   = alloc((size_t)N * 128);   // h
    float* xw1s = bufA;
    float* h    = bufB;
    float* xw2s = bufA;
    float* x1   = bufA + (size_t)N * 64;
    (void)ws_size;

    hipMemsetAsync(d_ws, 0, zfloats * sizeof(float), stream);

    // CSR build
    if ((N + 7) / 8 <= MAXNR) {
        place_hist_kernel<<<64, 1024, 0, stream>>>(rows, cols, ew, cnt, slot, ovf, ovfcnt, E, N);
    } else {
        place_simple_kernel<<<(E + 255) / 256, 256, 0, stream>>>(rows, cols, ew, cnt, slot, ovf, ovfcnt, E);
    }
    degfin_kernel<<<(N + 3) / 4, 256, 0, stream>>>(slot, cnt, ovf, ovfcnt, dinv, N);

    // Layer 1: 8 slices (per-XCD working set 3.2MB)
    gemm_kernel<128, 8><<<(N + 31) / 32, 256, 0, stream>>>(x, W1, dinv, xw1s, N);
    gather_kernel<128, 8><<<((N + 15) / 16) * 8, 256, 0, stream>>>(xw1s, slot, cnt, dinv, b1, ovf, ovfcnt, h, N);

    // Layer 2: 4 slices (SW stays 16 -> full line utilization)
    gemm_kernel<64, 4><<<(N + 63) / 64, 256, 0, stream>>>(h, W2, dinv, xw2s, N);
    gather_kernel<64, 4><<<((N + 15) / 16) * 4, 256, 0, stream>>>(xw2s, slot, cnt, dinv, b2, ovf, ovfcnt, x1, N);

    // Mean-pool + head
    pool_kernel<<<(N + 255) / 256, 256, 0, stream>>>(x1, batch, sums, cntf, N);
    head_kernel<<<1, 256, 0, stream>>>(sums, cntf, fc1W, fc1b, fc2W, fc2b, out);
}

// Round 7
// 409.710 us; speedup vs baseline: 1.4445x; 1.4445x over previous
//
#include <hip/hip_runtime.h>
#include <hip/hip_bf16.h>

// ---------------------------------------------------------------------------
// GCN: h = relu(GCNConv(x,W1,b1)); x1 = relu(GCNConv(h,W2,b2));
//      x2 = meanpool(x1,batch); out = log_softmax(relu(x2@fc1+b)@fc2+b)
//
// R7: R6's XCD-range histogram place (write locality + atomic dedup both
// confirmed by counters) but with 256 blocks (32 chunks x 8 ranges) instead
// of 64 -- R6 ran at 11.7% occupancy, latency-bound on 3 passes (290us).
// One block/CU, 16 waves/CU; ~1.0M deduped cnt atomics.
// ---------------------------------------------------------------------------

#define CAP 64
#define OVFCAP 8192
#define MAXNR 6400   // max nodes per range for the histogram place path
#define NCH 32       // edge chunks per range (grid = 8*NCH blocks)

// Histogram place: range r = blockIdx%8 (maps to XCD r), chunk j = blockIdx/8.
// Pass B: LDS histogram of chunk's in-range edges. Pass C: one global atomic
// per touched node reserves [g,g+h) in bucket. Pass D: write records at
// deterministic positions (LDS cursor). Stores are XCD-local -> L2-resident.
__global__ __launch_bounds__(1024)
void place_hist_kernel(const int* __restrict__ rows, const int* __restrict__ cols,
                       const float* __restrict__ ew, int* __restrict__ cnt,
                       unsigned* __restrict__ slot, int4* __restrict__ ovf,
                       int* __restrict__ ovfcnt, int E, int N) {
    __shared__ int hist[MAXNR];
    const int r = blockIdx.x & 7;
    const int j = blockIdx.x >> 3;
    const int nch = gridDim.x >> 3;
    const int NR = (N + 7) >> 3;
    const int base = r * NR;
    const int hi = min(base + NR, N);
    const int CS = (E + nch - 1) / nch;
    const int e0 = j * CS, e1 = min(e0 + CS, E);
    const int t = threadIdx.x;
    for (int n = t; n < NR; n += 1024) hist[n] = 0;
    __syncthreads();
    for (int e = e0 + t; e < e1; e += 1024) {
        int c = cols[e];
        if (c >= base && c < hi) atomicAdd(&hist[c - base], 1);
    }
    __syncthreads();
    for (int n = t; n < NR; n += 1024) {
        int h = hist[n];
        if (h > 0) hist[n] = atomicAdd(&cnt[base + n], h);   // global base
    }
    __syncthreads();
    for (int e = e0 + t; e < e1; e += 1024) {
        int c = cols[e];
        if (c >= base && c < hi) {
            int pos = atomicAdd(&hist[c - base], 1);          // LDS cursor
            int q = (int)(ew[e] * 32768.0f);
            if (q > 32767) q = 32767;
            unsigned rec = ((unsigned)rows[e] << 15) | (unsigned)q;
            if (pos < CAP) {
                slot[(size_t)c * CAP + pos] = rec;
            } else {
                int o = atomicAdd(ovfcnt, 1);
                if (o < OVFCAP) ovf[o] = make_int4(rows[e], c, q, 0);
            }
        }
    }
}

// Fallback for NR > MAXNR (not taken for this problem size): per-edge atomics.
__global__ void place_simple_kernel(const int* __restrict__ rows, const int* __restrict__ cols,
                                    const float* __restrict__ ew, int* __restrict__ cnt,
                                    unsigned* __restrict__ slot, int4* __restrict__ ovf,
                                    int* __restrict__ ovfcnt, int E) {
    int e = blockIdx.x * 256 + threadIdx.x;
    if (e >= E) return;
    int r = rows[e], c = cols[e];
    int q = (int)(ew[e] * 32768.0f);
    if (q > 32767) q = 32767;
    int pos = atomicAdd(&cnt[c], 1);
    if (pos < CAP) {
        slot[(size_t)c * CAP + pos] = ((unsigned)r << 15) | (unsigned)q;
    } else {
        int o = atomicAdd(ovfcnt, 1);
        if (o < OVFCAP) ovf[o] = make_int4(r, c, q, 0);
    }
}

// dinv[i] = rsqrt(sum of bucket weights (+ ovf entries if cnt>CAP) + 1).
__global__ void degfin_kernel(const unsigned* __restrict__ slot, const int* __restrict__ cnt,
                              const int4* __restrict__ ovf, const int* __restrict__ ovfcnt,
                              float* __restrict__ dinv, int N) {
    const int w = threadIdx.x >> 6, lane = threadIdx.x & 63;
    const int i = blockIdx.x * 4 + w;
    if (i >= N) return;
    int mraw = cnt[i];
    int m = mraw > CAP ? CAP : mraw;
    float v = 0.f;
    if (lane < m) v = (float)(slot[(size_t)i * CAP + lane] & 32767u);
    if (mraw > CAP) {
        int oc = *ovfcnt; if (oc > OVFCAP) oc = OVFCAP;
        for (int k = lane; k < oc; k += 64)
            if (ovf[k].y == i) v += (float)ovf[k].z;
    }
    #pragma unroll
    for (int off = 1; off < 64; off <<= 1) v += __shfl_xor(v, off);
    if (lane == 0) dinv[i] = rsqrtf(v * (1.0f / 32768.0f) + 1.0f);
}

// out_sliced[slice][M][SW] = (A[M][128] @ W[128][BN]) * dinv[row] * 2^-15.
template <int BN, int S>
__global__ void gemm_kernel(const float* __restrict__ A, const float* __restrict__ W,
                            const float* __restrict__ dinv, float* __restrict__ out, int M) {
    constexpr int K = 128;
    constexpr int BK = 32;
    constexpr int SW = BN / S;
    constexpr int CG = BN / 4;
    constexpr int RG = 256 / CG;
    constexpr int BM = RG * 4;
    __shared__ float xs[BM][BK + 4];
    __shared__ float ws[BK][BN];
    const int t = threadIdx.x;
    const int cg = t % CG, rg = t / CG;
    const int c0 = cg * 4, r0 = rg * 4;
    const int rowBase = blockIdx.x * BM;
    float acc[4][4] = {};
    for (int k0 = 0; k0 < K; k0 += BK) {
        constexpr int XL = BM * BK / (256 * 4);
        #pragma unroll
        for (int i = 0; i < XL; ++i) {
            int f = (t + i * 256) * 4;
            int rr = f / BK, kk = f % BK;
            int grow = rowBase + rr;
            float4 v = (grow < M) ? *(const float4*)&A[(size_t)grow * K + k0 + kk]
                                  : make_float4(0.f, 0.f, 0.f, 0.f);
            *(float4*)&xs[rr][kk] = v;
        }
        constexpr int WL = BK * BN / (256 * 4);
        #pragma unroll
        for (int i = 0; i < WL; ++i) {
            int f = (t + i * 256) * 4;
            int kk = f / BN, cc = f % BN;
            *(float4*)&ws[kk][cc] = *(const float4*)&W[(size_t)(k0 + kk) * BN + cc];
        }
        __syncthreads();
        #pragma unroll
        for (int kk = 0; kk < BK; ++kk) {
            float4 wv = *(float4*)&ws[kk][c0];
            float xv[4];
            #pragma unroll
            for (int i = 0; i < 4; ++i) xv[i] = xs[r0 + i][kk];
            #pragma unroll
            for (int i = 0; i < 4; ++i) {
                acc[i][0] += xv[i] * wv.x;
                acc[i][1] += xv[i] * wv.y;
                acc[i][2] += xv[i] * wv.z;
                acc[i][3] += xv[i] * wv.w;
            }
        }
        __syncthreads();
    }
    const int slice = c0 / SW, cw = c0 % SW;
    float* dst0 = out + (size_t)slice * M * SW + cw;
    #pragma unroll
    for (int i = 0; i < 4; ++i) {
        int grow = rowBase + r0 + i;
        if (grow < M) {
            float s = dinv[grow] * (1.0f / 32768.0f);
            *(float4*)&dst0[(size_t)grow * SW] =
                make_float4(acc[i][0] * s, acc[i][1] * s, acc[i][2] * s, acc[i][3] * s);
        }
    }
}

// Sliced aggregation (slice = blockIdx%S -> XCD-local sub-table). Wave handles
// 4 nodes (lane = nd*16 + e*4 + cg). Table prescaled by dinv[row]*2^-15 so
// coef = (float)q15. Overflow edges handled inline (cnt>CAP -> scan ovf).
// Epilogue: relu(d*acc + xs_self*(d*32768) + b).
template <int F, int S>
__global__ void gather_kernel(const float* __restrict__ xsb, const unsigned* __restrict__ slot,
                              const int* __restrict__ cnt, const float* __restrict__ dinv,
                              const float* __restrict__ b, const int4* __restrict__ ovf,
                              const int* __restrict__ ovfcnt, float* __restrict__ out, int N) {
    constexpr int SW = F / S;        // 16
    constexpr int LG = SW / 4;       // 4 lanes per edge
    constexpr int EPN = 4;           // edges in flight per node
    constexpr int NPW = 64 / (LG * EPN);  // 4 nodes per wave
    const int slice = blockIdx.x % S;
    const int grp = blockIdx.x / S;
    const int w = threadIdx.x >> 6, lane = threadIdx.x & 63;
    const int cg = lane % LG;
    const int e  = (lane / LG) % EPN;
    const int nd = lane / (LG * EPN);
    const int i = (grp * 4 + w) * NPW + nd;
    const bool iv = (i < N);
    const int ic = iv ? i : 0;
    const float4* xs4 = (const float4*)(xsb + (size_t)slice * N * SW);
    int mraw = iv ? cnt[ic] : 0;
    int m = mraw > CAP ? CAP : mraw;
    const unsigned* bkt = slot + (size_t)ic * CAP;
    float4 acc = make_float4(0.f, 0.f, 0.f, 0.f);
    int j = e;
    for (; j + EPN < m; j += 2 * EPN) {
        unsigned u0 = bkt[j], u1 = bkt[j + EPN];
        int r0 = u0 >> 15, r1 = u1 >> 15;
        float c0 = (float)(u0 & 32767u);
        float c1 = (float)(u1 & 32767u);
        float4 v0 = xs4[r0 * LG + cg];
        float4 v1 = xs4[r1 * LG + cg];
        acc.x += v0.x * c0 + v1.x * c1;
        acc.y += v0.y * c0 + v1.y * c1;
        acc.z += v0.z * c0 + v1.z * c1;
        acc.w += v0.w * c0 + v1.w * c1;
    }
    if (j < m) {
        unsigned u = bkt[j];
        int r = u >> 15;
        float c = (float)(u & 32767u);
        float4 v = xs4[r * LG + cg];
        acc.x += v.x * c; acc.y += v.y * c; acc.z += v.z * c; acc.w += v.w * c;
    }
    if (mraw > CAP) {                     // inline overflow (normally skipped)
        int oc = *ovfcnt; if (oc > OVFCAP) oc = OVFCAP;
        for (int k = e; k < oc; k += EPN) {
            int4 rec = ovf[k];
            if (rec.y == i) {
                float c = (float)rec.z;
                float4 v = xs4[rec.x * LG + cg];
                acc.x += v.x * c; acc.y += v.y * c; acc.z += v.z * c; acc.w += v.w * c;
            }
        }
    }
    // reduce over e (EPN=4): two butterfly steps
    acc.x += __shfl_xor(acc.x, LG);     acc.y += __shfl_xor(acc.y, LG);
    acc.z += __shfl_xor(acc.z, LG);     acc.w += __shfl_xor(acc.w, LG);
    acc.x += __shfl_xor(acc.x, 2 * LG); acc.y += __shfl_xor(acc.y, 2 * LG);
    acc.z += __shfl_xor(acc.z, 2 * LG); acc.w += __shfl_xor(acc.w, 2 * LG);
    if (e == 0 && iv) {
        float d = dinv[i];
        float sd = d * 32768.0f;
        float4 xv = xs4[i * LG + cg];
        float4 bb = *(const float4*)&b[slice * SW + cg * 4];
        float4 o;
        o.x = fmaxf(acc.x * d + xv.x * sd + bb.x, 0.f);
        o.y = fmaxf(acc.y * d + xv.y * sd + bb.y, 0.f);
        o.z = fmaxf(acc.z * d + xv.z * sd + bb.z, 0.f);
        o.w = fmaxf(acc.w * d + xv.w * sd + bb.w, 0.f);
        *(float4*)&out[(size_t)i * F + slice * SW + cg * 4] = o;
    }
}

// sums[batch[n]] += x1[n]; cnt[batch[n]] += 1 (sorted batch, boundary atomics)
__global__ void pool_kernel(const float* __restrict__ x1, const int* __restrict__ batch,
                            float* __restrict__ sums, float* __restrict__ cnt, int N) {
    constexpr int QG = 16, S = 16, ITER = 16;
    int t = threadIdx.x;
    int q = t % QG, s = t / QG;
    int n0 = blockIdx.x * (S * ITER) + s * ITER;
    float4 acc = make_float4(0.f, 0.f, 0.f, 0.f);
    float cacc = 0.f;
    int gcur = -1;
    for (int i = 0; i < ITER; ++i) {
        int n = n0 + i;
        if (n >= N) break;
        int gid = batch[n];
        if (gid != gcur) {
            if (gcur >= 0) {
                float* dst = &sums[gcur * 64 + q * 4];
                atomicAdd(dst + 0, acc.x);
                atomicAdd(dst + 1, acc.y);
                atomicAdd(dst + 2, acc.z);
                atomicAdd(dst + 3, acc.w);
                if (q == 0) atomicAdd(&cnt[gcur], cacc);
            }
            gcur = gid;
            acc = make_float4(0.f, 0.f, 0.f, 0.f);
            cacc = 0.f;
        }
        float4 a = ((const float4*)x1)[n * QG + q];
        acc.x += a.x; acc.y += a.y; acc.z += a.z; acc.w += a.w;
        if (q == 0) cacc += 1.f;
    }
    if (gcur >= 0) {
        float* dst = &sums[gcur * 64 + q * 4];
        atomicAdd(dst + 0, acc.x);
        atomicAdd(dst + 1, acc.y);
        atomicAdd(dst + 2, acc.z);
        atomicAdd(dst + 3, acc.w);
        if (q == 0) atomicAdd(&cnt[gcur], cacc);
    }
}

// Final MLP head + log_softmax, one block. G=64 graphs.
__global__ void head_kernel(const float* __restrict__ sums, const float* __restrict__ cnt,
                            const float* __restrict__ fc1W, const float* __restrict__ fc1b,
                            const float* __restrict__ fc2W, const float* __restrict__ fc2b,
                            float* __restrict__ out) {
    __shared__ float x2[64 * 64];
    __shared__ float h[64 * 128];
    __shared__ float logits[64 * 2];
    int t = threadIdx.x;
    for (int i = t; i < 64 * 64; i += 256) {
        int g = i / 64;
        x2[i] = sums[i] / fmaxf(cnt[g], 1.f);
    }
    __syncthreads();
    for (int i = t; i < 64 * 128; i += 256) {
        int g = i / 128, k = i % 128;
        float a = fc1b[k];
        #pragma unroll 8
        for (int j = 0; j < 64; ++j) a += x2[g * 64 + j] * fc1W[j * 128 + k];
        h[i] = fmaxf(a, 0.f);
    }
    __syncthreads();
    if (t < 128) {
        int g = t / 2, m = t % 2;
        float a = fc2b[m];
        #pragma unroll 8
        for (int k = 0; k < 128; ++k) a += h[g * 128 + k] * fc2W[k * 2 + m];
        logits[t] = a;
    }
    __syncthreads();
    if (t < 128) {
        int g = t / 2, m = t % 2;
        float l0 = logits[g * 2 + 0], l1 = logits[g * 2 + 1];
        float mx = fmaxf(l0, l1);
        float lse = mx + logf(expf(l0 - mx) + expf(l1 - mx));
        out[t] = (m == 0 ? l0 : l1) - lse;
    }
}

extern "C" void kernel_launch(void* const* d_in, const int* in_sizes, int n_in,
                              void* d_out, int out_size, void* d_ws, size_t ws_size,
                              hipStream_t stream) {
    const float* x      = (const float*)d_in[0];
    const int*   eidx   = (const int*)d_in[1];
    const float* ew     = (const float*)d_in[2];
    const int*   batch  = (const int*)d_in[3];
    const float* W1     = (const float*)d_in[4];
    const float* b1     = (const float*)d_in[5];
    const float* W2     = (const float*)d_in[6];
    const float* b2     = (const float*)d_in[7];
    const float* fc1W   = (const float*)d_in[8];
    const float* fc1b   = (const float*)d_in[9];
    const float* fc2W   = (const float*)d_in[10];
    const float* fc2b   = (const float*)d_in[11];
    float* out = (float*)d_out;

    const int N = in_sizes[3];          // 50000 nodes
    const int E = in_sizes[2];          // 1600000 edges
    const int* rows = eidx;
    const int* cols = eidx + E;

    float* ws = (float*)d_ws;
    size_t off = 0;
    auto alloc = [&](size_t n) { float* p = ws + off; off += (n + 15) & ~(size_t)15; return p; };
    // --- zero-initialized region ---
    int*      cnt    = (int*)alloc(N);
    float*    sums   = alloc(64 * 64);
    float*    cntf   = alloc(16);
    int*      ovfcnt = (int*)alloc(16);
    size_t zfloats = off;
    // --- rest ---
    float*    dinv   = alloc(N);
    unsigned* slot   = (unsigned*)alloc((size_t)N * CAP);
    int4*     ovf    = (int4*)alloc((size_t)OVFCAP * 4);
    float*    bufA   = alloc((size_t)N * 128);   // xw1s; later xw2s (lo) + x1 (hi)
    float*    bufB   = alloc((size_t)N * 128);   // h
    float* xw1s = bufA;
    float* h    = bufB;
    float* xw2s = bufA;
    float* x1   = bufA + (size_t)N * 64;
    (void)ws_size;

    hipMemsetAsync(d_ws, 0, zfloats * sizeof(float), stream);

    // CSR build
    if ((N + 7) / 8 <= MAXNR) {
        place_hist_kernel<<<8 * NCH, 1024, 0, stream>>>(rows, cols, ew, cnt, slot, ovf, ovfcnt, E, N);
    } else {
        place_simple_kernel<<<(E + 255) / 256, 256, 0, stream>>>(rows, cols, ew, cnt, slot, ovf, ovfcnt, E);
    }
    degfin_kernel<<<(N + 3) / 4, 256, 0, stream>>>(slot, cnt, ovf, ovfcnt, dinv, N);

    // Layer 1: 8 slices (per-XCD working set 3.2MB)
    gemm_kernel<128, 8><<<(N + 31) / 32, 256, 0, stream>>>(x, W1, dinv, xw1s, N);
    gather_kernel<128, 8><<<((N + 15) / 16) * 8, 256, 0, stream>>>(xw1s, slot, cnt, dinv, b1, ovf, ovfcnt, h, N);

    // Layer 2: 4 slices (SW stays 16 -> full line utilization)
    gemm_kernel<64, 4><<<(N + 63) / 64, 256, 0, stream>>>(h, W2, dinv, xw2s, N);
    gather_kernel<64, 4><<<((N + 15) / 16) * 4, 256, 0, stream>>>(xw2s, slot, cnt, dinv, b2, ovf, ovfcnt, x1, N);

    // Mean-pool + head
    pool_kernel<<<(N + 255) / 256, 256, 0, stream>>>(x1, batch, sums, cntf, N);
    head_kernel<<<1, 256, 0, stream>>>(sums, cntf, fc1W, fc1b, fc2W, fc2b, out);
}

// Round 8
// 352.609 us; speedup vs baseline: 1.6784x; 1.1619x over previous
//
#include <hip/hip_runtime.h>
#include <hip/hip_bf16.h>

// ---------------------------------------------------------------------------
// GCN: h = relu(GCNConv(x,W1,b1)); x1 = relu(GCNConv(h,W2,b2));
//      x2 = meanpool(x1,batch); out = log_softmax(relu(x2@fc1+b)@fc2+b)
//
// R8: (a) CSR build is now a two-phase partition pipeline with NO redundant
// range scans (R7: each edge chunk scanned by 8 range-blocks = ~1.6GB L2-side
// traffic, 93us) and NO contended reserve atomics (deterministic per-chunk
// bases via h2d prefix). (b) gather tables stored bf16 -> 64B line covers 32
// features, so layer1 needs 4 slices / layer2 2 (was 8/4): slot re-reads and
// edge line traffic halve. absmax budget: bf16 rel 2^-9 on messages ~1e-3.
// ---------------------------------------------------------------------------

#define CAP 64
#define OVFCAP 8192
#define MAXNR 6400   // max nodes per range (LDS histogram)
#define PCH 32       // chunks per range in the place pipeline

__device__ inline unsigned short f2bf(float f) {   // fp32 -> bf16 RNE
    unsigned u = __float_as_uint(f);
    u += 0x7FFFu + ((u >> 16) & 1u);
    return (unsigned short)(u >> 16);
}

// P1: partition edges into 8 per-range lists rng[r] of (col, row<<15|q15(ew)).
// 8 LDS counters per block; 8 global atomics per block (2048 total).
__global__ void part_kernel(const int* __restrict__ rows, const int* __restrict__ cols,
                            const float* __restrict__ ew, int* __restrict__ rangeCnt,
                            uint2* __restrict__ rng, int E, int NR, int RSEG) {
    __shared__ int hc[8];
    const int t = threadIdx.x;
    const int nb = gridDim.x;
    const int CS = (E + nb - 1) / nb;
    const int e0 = blockIdx.x * CS, e1 = min(e0 + CS, E);
    if (t < 8) hc[t] = 0;
    __syncthreads();
    for (int e = e0 + t; e < e1; e += 256) {
        int r = cols[e] / NR;
        atomicAdd(&hc[r], 1);
    }
    __syncthreads();
    if (t < 8) hc[t] = atomicAdd(&rangeCnt[t], hc[t]);   // hc becomes cursor base
    __syncthreads();
    for (int e = e0 + t; e < e1; e += 256) {
        int c = cols[e];
        int r = c / NR;
        int q = (int)(ew[e] * 32768.0f);
        if (q > 32767) q = 32767;
        unsigned rec = ((unsigned)rows[e] << 15) | (unsigned)q;
        int pos = atomicAdd(&hc[r], 1);
        if (pos < RSEG) rng[(size_t)r * RSEG + pos] = make_uint2((unsigned)c, rec);
        // pos>=RSEG impossible for RSEG = E/8 + 32K unless wildly skewed input
    }
}

// P2a: per-(range,chunk) LDS histogram -> h2d[(r*PCH+j)*NR + c]
__global__ __launch_bounds__(1024)
void hist2_kernel(const uint2* __restrict__ rng, const int* __restrict__ rangeCnt,
                  int* __restrict__ h2d, int NR, int RSEG) {
    __shared__ int hist[MAXNR];
    const int r = blockIdx.x & 7, j = blockIdx.x >> 3;
    const int t = threadIdx.x;
    const int M = min(rangeCnt[r], RSEG);
    const int CS = (M + PCH - 1) / PCH;
    const int e0 = j * CS, e1 = min(e0 + CS, M);
    for (int n = t; n < NR; n += 1024) hist[n] = 0;
    __syncthreads();
    const uint2* lst = rng + (size_t)r * RSEG;
    for (int k = e0 + t; k < e1; k += 1024)
        atomicAdd(&hist[lst[k].x - r * NR], 1);
    __syncthreads();
    int* dst = h2d + (size_t)(r * PCH + j) * NR;
    for (int n = t; n < NR; n += 1024) dst[n] = hist[n];
}

// P2b: per-node exclusive prefix over the PCH chunk counts -> bases in-place,
// total -> cnt[n].  Zero atomics, fully deterministic.
__global__ void scan2_kernel(int* __restrict__ h2d, int* __restrict__ cnt, int NR, int N) {
    int n = blockIdx.x * 256 + threadIdx.x;
    if (n >= N) return;
    int r = n / NR, c = n - r * NR;
    int* col = h2d + (size_t)(r * PCH) * NR + c;
    int run = 0;
    #pragma unroll 8
    for (int j = 0; j < PCH; ++j) {
        int v = col[(size_t)j * NR];
        col[(size_t)j * NR] = run;
        run += v;
    }
    cnt[n] = run;
}

// P2c: write slot records at deterministic positions (chunk base + LDS cursor).
__global__ __launch_bounds__(1024)
void place2_kernel(const uint2* __restrict__ rng, const int* __restrict__ rangeCnt,
                   const int* __restrict__ h2d, unsigned* __restrict__ slot,
                   int4* __restrict__ ovf, int* __restrict__ ovfcnt,
                   int NR, int RSEG) {
    __shared__ int cur[MAXNR];
    const int r = blockIdx.x & 7, j = blockIdx.x >> 3;
    const int t = threadIdx.x;
    const int M = min(rangeCnt[r], RSEG);
    const int CS = (M + PCH - 1) / PCH;
    const int e0 = j * CS, e1 = min(e0 + CS, M);
    const int* src = h2d + (size_t)(r * PCH + j) * NR;
    for (int n = t; n < NR; n += 1024) cur[n] = src[n];
    __syncthreads();
    const uint2* lst = rng + (size_t)r * RSEG;
    for (int k = e0 + t; k < e1; k += 1024) {
        uint2 u2 = lst[k];
        int pos = atomicAdd(&cur[u2.x - r * NR], 1);   // LDS cursor
        if (pos < CAP) {
            slot[(size_t)u2.x * CAP + pos] = u2.y;
        } else {
            int o = atomicAdd(ovfcnt, 1);
            if (o < OVFCAP)
                ovf[o] = make_int4((int)(u2.y >> 15), (int)u2.x, (int)(u2.y & 32767u), 0);
        }
    }
}

// Fallback for N too large for LDS histogram (not taken here).
__global__ void place_simple_kernel(const int* __restrict__ rows, const int* __restrict__ cols,
                                    const float* __restrict__ ew, int* __restrict__ cnt,
                                    unsigned* __restrict__ slot, int4* __restrict__ ovf,
                                    int* __restrict__ ovfcnt, int E) {
    int e = blockIdx.x * 256 + threadIdx.x;
    if (e >= E) return;
    int r = rows[e], c = cols[e];
    int q = (int)(ew[e] * 32768.0f);
    if (q > 32767) q = 32767;
    int pos = atomicAdd(&cnt[c], 1);
    if (pos < CAP) {
        slot[(size_t)c * CAP + pos] = ((unsigned)r << 15) | (unsigned)q;
    } else {
        int o = atomicAdd(ovfcnt, 1);
        if (o < OVFCAP) ovf[o] = make_int4(r, c, q, 0);
    }
}

// dinv[i] = rsqrt(sum of bucket weights (+ ovf entries if cnt>CAP) + 1).
__global__ void degfin_kernel(const unsigned* __restrict__ slot, const int* __restrict__ cnt,
                              const int4* __restrict__ ovf, const int* __restrict__ ovfcnt,
                              float* __restrict__ dinv, int N) {
    const int w = threadIdx.x >> 6, lane = threadIdx.x & 63;
    const int i = blockIdx.x * 4 + w;
    if (i >= N) return;
    int mraw = cnt[i];
    int m = mraw > CAP ? CAP : mraw;
    float v = 0.f;
    if (lane < m) v = (float)(slot[(size_t)i * CAP + lane] & 32767u);
    if (mraw > CAP) {
        int oc = *ovfcnt; if (oc > OVFCAP) oc = OVFCAP;
        for (int k = lane; k < oc; k += 64)
            if (ovf[k].y == i) v += (float)ovf[k].z;
    }
    #pragma unroll
    for (int off = 1; off < 64; off <<= 1) v += __shfl_xor(v, off);
    if (lane == 0) dinv[i] = rsqrtf(v * (1.0f / 32768.0f) + 1.0f);
}

// outbf[slice][M][32] (bf16) = (A[M][128] @ W[128][BN]) * dinv[row] * 2^-15.
// Slice width fixed at 32 bf16 = 64B line. S = BN/32 slices.
template <int BN, int S>
__global__ void gemm_kernel(const float* __restrict__ A, const float* __restrict__ W,
                            const float* __restrict__ dinv, unsigned short* __restrict__ outbf,
                            int M) {
    constexpr int K = 128;
    constexpr int BK = 32;
    constexpr int CG = BN / 4;
    constexpr int RG = 256 / CG;
    constexpr int BM = RG * 4;
    __shared__ float xs[BM][BK + 4];
    __shared__ float ws[BK][BN];
    const int t = threadIdx.x;
    const int cg = t % CG, rg = t / CG;
    const int c0 = cg * 4, r0 = rg * 4;
    const int rowBase = blockIdx.x * BM;
    float acc[4][4] = {};
    for (int k0 = 0; k0 < K; k0 += BK) {
        constexpr int XL = BM * BK / (256 * 4);
        #pragma unroll
        for (int i = 0; i < XL; ++i) {
            int f = (t + i * 256) * 4;
            int rr = f / BK, kk = f % BK;
            int grow = rowBase + rr;
            float4 v = (grow < M) ? *(const float4*)&A[(size_t)grow * K + k0 + kk]
                                  : make_float4(0.f, 0.f, 0.f, 0.f);
            *(float4*)&xs[rr][kk] = v;
        }
        constexpr int WL = BK * BN / (256 * 4);
        #pragma unroll
        for (int i = 0; i < WL; ++i) {
            int f = (t + i * 256) * 4;
            int kk = f / BN, cc = f % BN;
            *(float4*)&ws[kk][cc] = *(const float4*)&W[(size_t)(k0 + kk) * BN + cc];
        }
        __syncthreads();
        #pragma unroll
        for (int kk = 0; kk < BK; ++kk) {
            float4 wv = *(float4*)&ws[kk][c0];
            float xv[4];
            #pragma unroll
            for (int i = 0; i < 4; ++i) xv[i] = xs[r0 + i][kk];
            #pragma unroll
            for (int i = 0; i < 4; ++i) {
                acc[i][0] += xv[i] * wv.x;
                acc[i][1] += xv[i] * wv.y;
                acc[i][2] += xv[i] * wv.z;
                acc[i][3] += xv[i] * wv.w;
            }
        }
        __syncthreads();
    }
    const int slice = c0 >> 5, cw = c0 & 31;
    #pragma unroll
    for (int i = 0; i < 4; ++i) {
        int grow = rowBase + r0 + i;
        if (grow < M) {
            float s = dinv[grow] * (1.0f / 32768.0f);
            unsigned p0 = (unsigned)f2bf(acc[i][0] * s) | ((unsigned)f2bf(acc[i][1] * s) << 16);
            unsigned p1 = (unsigned)f2bf(acc[i][2] * s) | ((unsigned)f2bf(acc[i][3] * s) << 16);
            *(uint2*)&outbf[((size_t)slice * M + grow) * 32 + cw] = make_uint2(p0, p1);
        }
    }
}

// Sliced bf16 aggregation. slice = blockIdx%S -> XCD-group-local 3.2MB
// sub-table [N][32 bf16] (64B/node). Wave: 4 nodes x 4 edges-in-flight x
// 4 lanes/edge (uint4 = 8 bf16 each). Table prescaled by dinv[row]*2^-15 so
// coef = (float)q15. Epilogue: relu(d*acc + self*(d*32768) + b) in fp32.
template <int F, int S>
__global__ void gather_kernel(const unsigned short* __restrict__ xsb,
                              const unsigned* __restrict__ slot,
                              const int* __restrict__ cnt, const float* __restrict__ dinv,
                              const float* __restrict__ b, const int4* __restrict__ ovf,
                              const int* __restrict__ ovfcnt, float* __restrict__ out, int N) {
    constexpr int LG = 4;            // lanes per edge (4 x 16B = 64B line)
    constexpr int EPN = 4;           // edges in flight per node
    const int slice = blockIdx.x % S;
    const int grp = blockIdx.x / S;
    const int w = threadIdx.x >> 6, lane = threadIdx.x & 63;
    const int cg = lane & 3;
    const int e  = (lane >> 2) & 3;
    const int nd = lane >> 4;
    const int i = (grp * 4 + w) * 4 + nd;
    const bool iv = (i < N);
    const int ic = iv ? i : 0;
    const uint4* xs4 = (const uint4*)(xsb + (size_t)slice * N * 32);
    int mraw = iv ? cnt[ic] : 0;
    int m = mraw > CAP ? CAP : mraw;
    const unsigned* bkt = slot + (size_t)ic * CAP;
    float acc[8] = {};
    int j = e;
    for (; j + EPN < m; j += 2 * EPN) {
        unsigned u0 = bkt[j], u1 = bkt[j + EPN];
        float c0 = (float)(u0 & 32767u), c1 = (float)(u1 & 32767u);
        uint4 a0 = xs4[(size_t)(u0 >> 15) * 4 + cg];
        uint4 a1 = xs4[(size_t)(u1 >> 15) * 4 + cg];
        acc[0] += __uint_as_float(a0.x << 16) * c0 + __uint_as_float(a1.x << 16) * c1;
        acc[1] += __uint_as_float(a0.x & 0xFFFF0000u) * c0 + __uint_as_float(a1.x & 0xFFFF0000u) * c1;
        acc[2] += __uint_as_float(a0.y << 16) * c0 + __uint_as_float(a1.y << 16) * c1;
        acc[3] += __uint_as_float(a0.y & 0xFFFF0000u) * c0 + __uint_as_float(a1.y & 0xFFFF0000u) * c1;
        acc[4] += __uint_as_float(a0.z << 16) * c0 + __uint_as_float(a1.z << 16) * c1;
        acc[5] += __uint_as_float(a0.z & 0xFFFF0000u) * c0 + __uint_as_float(a1.z & 0xFFFF0000u) * c1;
        acc[6] += __uint_as_float(a0.w << 16) * c0 + __uint_as_float(a1.w << 16) * c1;
        acc[7] += __uint_as_float(a0.w & 0xFFFF0000u) * c0 + __uint_as_float(a1.w & 0xFFFF0000u) * c1;
    }
    if (j < m) {
        unsigned u = bkt[j];
        float c = (float)(u & 32767u);
        uint4 a = xs4[(size_t)(u >> 15) * 4 + cg];
        acc[0] += __uint_as_float(a.x << 16) * c;
        acc[1] += __uint_as_float(a.x & 0xFFFF0000u) * c;
        acc[2] += __uint_as_float(a.y << 16) * c;
        acc[3] += __uint_as_float(a.y & 0xFFFF0000u) * c;
        acc[4] += __uint_as_float(a.z << 16) * c;
        acc[5] += __uint_as_float(a.z & 0xFFFF0000u) * c;
        acc[6] += __uint_as_float(a.w << 16) * c;
        acc[7] += __uint_as_float(a.w & 0xFFFF0000u) * c;
    }
    if (mraw > CAP) {                     // inline overflow (normally skipped)
        int oc = *ovfcnt; if (oc > OVFCAP) oc = OVFCAP;
        for (int k = e; k < oc; k += EPN) {
            int4 rec = ovf[k];
            if (rec.y == i) {
                float c = (float)rec.z;
                uint4 a = xs4[(size_t)rec.x * 4 + cg];
                acc[0] += __uint_as_float(a.x << 16) * c;
                acc[1] += __uint_as_float(a.x & 0xFFFF0000u) * c;
                acc[2] += __uint_as_float(a.y << 16) * c;
                acc[3] += __uint_as_float(a.y & 0xFFFF0000u) * c;
                acc[4] += __uint_as_float(a.z << 16) * c;
                acc[5] += __uint_as_float(a.z & 0xFFFF0000u) * c;
                acc[6] += __uint_as_float(a.w << 16) * c;
                acc[7] += __uint_as_float(a.w & 0xFFFF0000u) * c;
            }
        }
    }
    #pragma unroll
    for (int k = 0; k < 8; ++k) {
        acc[k] += __shfl_xor(acc[k], 4);
        acc[k] += __shfl_xor(acc[k], 8);
    }
    if (e == 0 && iv) {
        float d = dinv[i];
        float sd = d * 32768.0f;
        uint4 sv = xs4[(size_t)i * 4 + cg];
        float s0 = __uint_as_float(sv.x << 16),        s1 = __uint_as_float(sv.x & 0xFFFF0000u);
        float s2 = __uint_as_float(sv.y << 16),        s3 = __uint_as_float(sv.y & 0xFFFF0000u);
        float s4 = __uint_as_float(sv.z << 16),        s5 = __uint_as_float(sv.z & 0xFFFF0000u);
        float s6 = __uint_as_float(sv.w << 16),        s7 = __uint_as_float(sv.w & 0xFFFF0000u);
        const float* bb = &b[slice * 32 + cg * 8];
        float4 bb0 = *(const float4*)&bb[0];
        float4 bb1 = *(const float4*)&bb[4];
        float4 o0, o1;
        o0.x = fmaxf(acc[0] * d + s0 * sd + bb0.x, 0.f);
        o0.y = fmaxf(acc[1] * d + s1 * sd + bb0.y, 0.f);
        o0.z = fmaxf(acc[2] * d + s2 * sd + bb0.z, 0.f);
        o0.w = fmaxf(acc[3] * d + s3 * sd + bb0.w, 0.f);
        o1.x = fmaxf(acc[4] * d + s4 * sd + bb1.x, 0.f);
        o1.y = fmaxf(acc[5] * d + s5 * sd + bb1.y, 0.f);
        o1.z = fmaxf(acc[6] * d + s6 * sd + bb1.z, 0.f);
        o1.w = fmaxf(acc[7] * d + s7 * sd + bb1.w, 0.f);
        float* dst = &out[(size_t)i * F + slice * 32 + cg * 8];
        *(float4*)&dst[0] = o0;
        *(float4*)&dst[4] = o1;
    }
}

// sums[batch[n]] += x1[n]; cnt[batch[n]] += 1 (sorted batch, boundary atomics)
__global__ void pool_kernel(const float* __restrict__ x1, const int* __restrict__ batch,
                            float* __restrict__ sums, float* __restrict__ cnt, int N) {
    constexpr int QG = 16, S = 16, ITER = 16;
    int t = threadIdx.x;
    int q = t % QG, s = t / QG;
    int n0 = blockIdx.x * (S * ITER) + s * ITER;
    float4 acc = make_float4(0.f, 0.f, 0.f, 0.f);
    float cacc = 0.f;
    int gcur = -1;
    for (int i = 0; i < ITER; ++i) {
        int n = n0 + i;
        if (n >= N) break;
        int gid = batch[n];
        if (gid != gcur) {
            if (gcur >= 0) {
                float* dst = &sums[gcur * 64 + q * 4];
                atomicAdd(dst + 0, acc.x);
                atomicAdd(dst + 1, acc.y);
                atomicAdd(dst + 2, acc.z);
                atomicAdd(dst + 3, acc.w);
                if (q == 0) atomicAdd(&cnt[gcur], cacc);
            }
            gcur = gid;
            acc = make_float4(0.f, 0.f, 0.f, 0.f);
            cacc = 0.f;
        }
        float4 a = ((const float4*)x1)[n * QG + q];
        acc.x += a.x; acc.y += a.y; acc.z += a.z; acc.w += a.w;
        if (q == 0) cacc += 1.f;
    }
    if (gcur >= 0) {
        float* dst = &sums[gcur * 64 + q * 4];
        atomicAdd(dst + 0, acc.x);
        atomicAdd(dst + 1, acc.y);
        atomicAdd(dst + 2, acc.z);
        atomicAdd(dst + 3, acc.w);
        if (q == 0) atomicAdd(&cnt[gcur], cacc);
    }
}

// Final MLP head + log_softmax, one block. G=64 graphs.
__global__ void head_kernel(const float* __restrict__ sums, const float* __restrict__ cnt,
                            const float* __restrict__ fc1W, const float* __restrict__ fc1b,
                            const float* __restrict__ fc2W, const float* __restrict__ fc2b,
                            float* __restrict__ out) {
    __shared__ float x2[64 * 64];
    __shared__ float h[64 * 128];
    __shared__ float logits[64 * 2];
    int t = threadIdx.x;
    for (int i = t; i < 64 * 64; i += 256) {
        int g = i / 64;
        x2[i] = sums[i] / fmaxf(cnt[g], 1.f);
    }
    __syncthreads();
    for (int i = t; i < 64 * 128; i += 256) {
        int g = i / 128, k = i % 128;
        float a = fc1b[k];
        #pragma unroll 8
        for (int j = 0; j < 64; ++j) a += x2[g * 64 + j] * fc1W[j * 128 + k];
        h[i] = fmaxf(a, 0.f);
    }
    __syncthreads();
    if (t < 128) {
        int g = t / 2, m = t % 2;
        float a = fc2b[m];
        #pragma unroll 8
        for (int k = 0; k < 128; ++k) a += h[g * 128 + k] * fc2W[k * 2 + m];
        logits[t] = a;
    }
    __syncthreads();
    if (t < 128) {
        int g = t / 2, m = t % 2;
        float l0 = logits[g * 2 + 0], l1 = logits[g * 2 + 1];
        float mx = fmaxf(l0, l1);
        float lse = mx + logf(expf(l0 - mx) + expf(l1 - mx));
        out[t] = (m == 0 ? l0 : l1) - lse;
    }
}

extern "C" void kernel_launch(void* const* d_in, const int* in_sizes, int n_in,
                              void* d_out, int out_size, void* d_ws, size_t ws_size,
                              hipStream_t stream) {
    const float* x      = (const float*)d_in[0];
    const int*   eidx   = (const int*)d_in[1];
    const float* ew     = (const float*)d_in[2];
    const int*   batch  = (const int*)d_in[3];
    const float* W1     = (const float*)d_in[4];
    const float* b1     = (const float*)d_in[5];
    const float* W2     = (const float*)d_in[6];
    const float* b2     = (const float*)d_in[7];
    const float* fc1W   = (const float*)d_in[8];
    const float* fc1b   = (const float*)d_in[9];
    const float* fc2W   = (const float*)d_in[10];
    const float* fc2b   = (const float*)d_in[11];
    float* out = (float*)d_out;

    const int N = in_sizes[3];          // 50000 nodes
    const int E = in_sizes[2];          // 1600000 edges
    const int* rows = eidx;
    const int* cols = eidx + E;
    const int NR = (N + 7) / 8;
    const int RSEG = E / 8 + 32768;

    float* ws = (float*)d_ws;
    size_t off = 0;
    auto alloc = [&](size_t n) { float* p = ws + off; off += (n + 15) & ~(size_t)15; return p; };
    // --- zero-initialized region ---
    float*    sums     = alloc(64 * 64);
    float*    cntf     = alloc(16);
    int*      ovfcnt   = (int*)alloc(16);
    int*      rangeCnt = (int*)alloc(16);
    int*      cnt      = (int*)alloc(N);          // zeroed for fallback path only
    size_t zfloats = off;
    // --- rest ---
    float*    dinv   = alloc(N);
    unsigned* slot   = (unsigned*)alloc((size_t)N * CAP);
    int4*     ovf    = (int4*)alloc((size_t)OVFCAP * 4);
    float*    bufA   = alloc((size_t)N * 128);   // h2d | xw1bf | xw2bf + x1
    float*    bufB   = alloc((size_t)N * 128);   // rng | h
    int*            h2d   = (int*)bufA;                       // 8*PCH*NR ints, dead before xw1bf
    unsigned short* xw1bf = (unsigned short*)bufA;            // [4][N][32] bf16
    unsigned short* xw2bf = (unsigned short*)bufA;            // [2][N][32] bf16
    float*          x1    = bufA + (size_t)N * 32;            // after xw2bf (N*64 ushorts)
    uint2*          rng   = (uint2*)bufB;                     // 8*RSEG uint2, dead before h
    float*          h     = bufB;
    (void)ws_size;

    hipMemsetAsync(d_ws, 0, zfloats * sizeof(float), stream);

    // CSR build: partition -> histogram -> prefix -> place (no contended atomics)
    if (NR <= MAXNR) {
        part_kernel<<<256, 256, 0, stream>>>(rows, cols, ew, rangeCnt, rng, E, NR, RSEG);
        hist2_kernel<<<8 * PCH, 1024, 0, stream>>>(rng, rangeCnt, h2d, NR, RSEG);
        scan2_kernel<<<(N + 255) / 256, 256, 0, stream>>>(h2d, cnt, NR, N);
        place2_kernel<<<8 * PCH, 1024, 0, stream>>>(rng, rangeCnt, h2d, slot, ovf, ovfcnt, NR, RSEG);
    } else {
        place_simple_kernel<<<(E + 255) / 256, 256, 0, stream>>>(rows, cols, ew, cnt, slot, ovf, ovfcnt, E);
    }
    degfin_kernel<<<(N + 3) / 4, 256, 0, stream>>>(slot, cnt, ovf, ovfcnt, dinv, N);

    // Layer 1: bf16 table, 4 slices of 32 features (3.2MB per XCD-group)
    gemm_kernel<128, 4><<<(N + 31) / 32, 256, 0, stream>>>(x, W1, dinv, xw1bf, N);
    gather_kernel<128, 4><<<((N + 15) / 16) * 4, 256, 0, stream>>>(xw1bf, slot, cnt, dinv, b1, ovf, ovfcnt, h, N);

    // Layer 2: bf16 table, 2 slices of 32 features
    gemm_kernel<64, 2><<<(N + 63) / 64, 256, 0, stream>>>(h, W2, dinv, xw2bf, N);
    gather_kernel<64, 2><<<((N + 15) / 16) * 2, 256, 0, stream>>>(xw2bf, slot, cnt, dinv, b2, ovf, ovfcnt, x1, N);

    // Mean-pool + head
    pool_kernel<<<(N + 255) / 256, 256, 0, stream>>>(x1, batch, sums, cntf, N);
    head_kernel<<<1, 256, 0, stream>>>(sums, cntf, fc1W, fc1b, fc2W, fc2b, out);
}